// Round 7
// baseline (882.547 us; speedup 1.0000x reference)
//
#include <hip/hip_runtime.h>
#include <hip/hip_bf16.h>
#include <math.h>

#define NTOK 8192
#define DM 512
#define DFF 2048
#define NE 8
#define ROWCAP 33792   // 32768 assignments max + 8*128 granule padding

typedef __attribute__((ext_vector_type(8))) short bfrag;
typedef __attribute__((ext_vector_type(4))) float f32x4;
typedef __attribute__((ext_vector_type(4))) unsigned int u32x4;
typedef __attribute__((ext_vector_type(4))) short s16x4;

__device__ __forceinline__ short f2bf(float f) {
  unsigned u = __builtin_bit_cast(unsigned, f);
  u += 0x7fffu + ((u >> 16) & 1u);
  return (short)(u >> 16);
}
__device__ __forceinline__ float bf2f(short s) {
  unsigned u = ((unsigned)(unsigned short)s) << 16;
  return __builtin_bit_cast(float, u);
}
// tanh-form GELU via hw exp2+rcp (~7 ops). max |diff vs erf-gelu| ~5e-4.
__device__ __forceinline__ float fast_gelu(float v) {
  float u = fmaf(v * v * v, 0.044715f, v) * 0.7978845608f;
  float ex = __builtin_amdgcn_exp2f(u * -2.8853900818f);
  return v * __builtin_amdgcn_rcpf(1.f + ex);
}

// ---------------- fp32 -> bf16 conversion ----------------
__global__ __launch_bounds__(256) void cvt_kernel(const float* __restrict__ in,
                                                  short* __restrict__ o, int n4) {
  int i = blockIdx.x * 256 + threadIdx.x;
  if (i >= n4) return;
  f32x4 v = ((const f32x4*)in)[i];
  s16x4 s;
  #pragma unroll
  for (int j = 0; j < 4; j++) s[j] = f2bf(v[j]);
  ((s16x4*)o)[i] = s;
}

// ---------------- fp32 -> bf16 transpose-convert ----------------
__global__ __launch_bounds__(256) void cvtT_kernel(const float* __restrict__ in,
                                                   short* __restrict__ o, int R, int C) {
  __shared__ float t[32][33];
  size_t eoff = (size_t)blockIdx.z * R * C;
  in += eoff; o += eoff;
  int r0 = blockIdx.x * 32, c0 = blockIdx.y * 32;
  int tx = threadIdx.x & 31, ty = threadIdx.x >> 5;
  #pragma unroll
  for (int i = 0; i < 32; i += 8)
    t[ty + i][tx] = in[(size_t)(r0 + ty + i) * C + c0 + tx];
  __syncthreads();
  #pragma unroll
  for (int i = 0; i < 32; i += 8)
    o[(size_t)(c0 + ty + i) * R + r0 + tx] = f2bf(t[tx][ty + i]);
}

// ---------------- router ----------------
__global__ __launch_bounds__(256) void router_kernel(const float* __restrict__ x,
                                                     const float* __restrict__ rw,
                                                     int* __restrict__ sel_e,
                                                     float* __restrict__ sel_w,
                                                     float* __restrict__ part) {
  __shared__ float s_cnt[NE], s_ps[NE];
  int tid = threadIdx.x;
  if (tid < NE) { s_cnt[tid] = 0.f; s_ps[tid] = 0.f; }
  __syncthreads();
  int wave = tid >> 6, lane = tid & 63;
  float myc[NE], myp[NE];
  #pragma unroll
  for (int e = 0; e < NE; e++) { myc[e] = 0.f; myp[e] = 0.f; }

  for (int i = 0; i < 8; i++) {
    int token = blockIdx.x * 32 + wave * 8 + i;
    const float* xt = x + (size_t)token * DM;
    float acc[NE];
    #pragma unroll
    for (int e = 0; e < NE; e++) acc[e] = 0.f;
    #pragma unroll
    for (int kk = 0; kk < DM / 64; kk++) {
      int k = kk * 64 + lane;
      float xv = xt[k];
      f32x4 r0 = *(const f32x4*)(rw + k * NE);
      f32x4 r1 = *(const f32x4*)(rw + k * NE + 4);
      acc[0] += xv * r0[0]; acc[1] += xv * r0[1]; acc[2] += xv * r0[2]; acc[3] += xv * r0[3];
      acc[4] += xv * r1[0]; acc[5] += xv * r1[1]; acc[6] += xv * r1[2]; acc[7] += xv * r1[3];
    }
    #pragma unroll
    for (int off = 32; off >= 1; off >>= 1) {
      #pragma unroll
      for (int e = 0; e < NE; e++) acc[e] += __shfl_xor(acc[e], off, 64);
    }
    float mx = acc[0];
    #pragma unroll
    for (int e = 1; e < NE; e++) mx = fmaxf(mx, acc[e]);
    float p[NE]; float sum = 0.f;
    #pragma unroll
    for (int e = 0; e < NE; e++) { p[e] = expf(acc[e] - mx); sum += p[e]; }
    float inv = 1.f / sum;
    #pragma unroll
    for (int e = 0; e < NE; e++) p[e] *= inv;
    float sp[4]; int si[4]; unsigned used = 0;
    #pragma unroll
    for (int s = 0; s < 4; s++) {
      float bp = -1.f; int bi = 0;
      #pragma unroll
      for (int e = 0; e < NE; e++)
        if (!((used >> e) & 1u) && p[e] > bp) { bp = p[e]; bi = e; }
      used |= 1u << bi; sp[s] = bp; si[s] = bi;
    }
    float csum = 0.f, wsum = 0.f; bool keep[4];
    #pragma unroll
    for (int s = 0; s < 4; s++) {
      keep[s] = (s < 1) || (csum < 0.9f);
      csum += sp[s];
      if (keep[s]) wsum += sp[s];
    }
    wsum = fmaxf(wsum, 1e-9f);
    if (lane == 0) {
      #pragma unroll
      for (int s = 0; s < 4; s++) {
        sel_e[token * 4 + s] = keep[s] ? si[s] : -1;
        sel_w[token * 4 + s] = keep[s] ? sp[s] / wsum : 0.f;
      }
      #pragma unroll
      for (int e = 0; e < NE; e++) myp[e] += p[e];
      #pragma unroll
      for (int s = 0; s < 4; s++) if (keep[s]) myc[si[s]] += 1.f;
    }
  }
  if (lane == 0) {
    #pragma unroll
    for (int e = 0; e < NE; e++) { atomicAdd(&s_cnt[e], myc[e]); atomicAdd(&s_ps[e], myp[e]); }
  }
  __syncthreads();
  if (tid < NE) {
    part[blockIdx.x * 16 + tid] = s_cnt[tid];
    part[blockIdx.x * 16 + 8 + tid] = s_ps[tid];
  }
}

// ---------------- prep: parallel stat reduction -> aux + expert bases ----------------
__global__ __launch_bounds__(256) void prep_kernel(const float* __restrict__ part,
                                                   float* __restrict__ auxp,
                                                   int* __restrict__ meta) {
  __shared__ float red[16];
  int tid = threadIdx.x;
  if (tid < 16) red[tid] = 0.f;
  __syncthreads();
  float s = 0.f;
  #pragma unroll
  for (int m = 0; m < 16; m++) s += part[tid + m * 256];
  atomicAdd(&red[tid & 15], s);
  __syncthreads();
  if (tid == 0) {
    float tot = 0.f;
    for (int e = 0; e < NE; e++) tot += red[e];
    float t = fmaxf(tot, 1.f), acc = 0.f;
    for (int e = 0; e < NE; e++) acc += (red[e] / t) * (red[NE + e] / (float)NTOK);
    auxp[0] = 0.01f * (float)NE * acc;
    int off = 0;
    for (int e = 0; e < NE; e++) {
      int c = (int)(red[e] + 0.5f);
      meta[e] = c; meta[8 + e] = off;
      off += (c + 127) & ~127;   // 128-granule padding (M-tile = 128)
    }
  }
  if (tid < NE) meta[16 + tid] = 0;
}

// ---------------- build compact assignment lists ----------------
__global__ __launch_bounds__(256) void build_kernel(const int* __restrict__ sel_e,
                                                    const float* __restrict__ sel_w,
                                                    int* __restrict__ meta,
                                                    int* __restrict__ mlist,
                                                    float* __restrict__ wrow,
                                                    int* __restrict__ arow) {
  __shared__ int lcnt[NE], roff[NE];
  int tid = threadIdx.x;
  if (tid < NE) lcnt[tid] = 0;
  __syncthreads();
  int t = blockIdx.x * 32 + tid;
  int slots[4], es[4];
  bool active = tid < 32;
  if (active) {
    #pragma unroll
    for (int s = 0; s < 4; s++) {
      es[s] = sel_e[t * 4 + s];
      slots[s] = (es[s] >= 0) ? atomicAdd(&lcnt[es[s]], 1) : -1;
    }
  }
  __syncthreads();
  if (tid < NE) roff[tid] = atomicAdd(&meta[16 + tid], lcnt[tid]);
  __syncthreads();
  if (active) {
    #pragma unroll
    for (int s = 0; s < 4; s++) {
      int e = es[s];
      if (e >= 0) {
        int hrow = meta[8 + e] + roff[e] + slots[s];
        mlist[hrow] = t;
        wrow[hrow] = sel_w[t * 4 + s];
        arow[t * 4 + s] = hrow;
      } else {
        arow[t * 4 + s] = -1;
      }
    }
  }
}

// ============ LDS-free "flatmm" GEMMs ============
// Block = 4 waves (2x2), block tile 128x128; each wave computes a 64x64 tile.
// A and B MFMA fragments are loaded DIRECTLY from global to VGPRs
// (global_load_dwordx4 per frag per lane: row = frag row + l16, bytes
// [kt+quad*8 .. +8)). No LDS, no barriers, no global_load_lds. Pipelined
// with two fragment sets (unroll-2 ping-pong) — compiler emits fine-grained
// per-register vmcnt so next-iter loads stay in flight under current MFMAs.
// L1 dedups the 2x intra-block fragment duplication (waves sharing wm / wn).

// ---------------- GEMM1: H[hrow] = bf16(gelu(x[tok] @ W1^T + b1)) ----------------
__global__ __launch_bounds__(256) void gemm1_sp(const short* __restrict__ A,
                                                const short* __restrict__ W1t,
                                                const float* __restrict__ b1,
                                                short* __restrict__ H,
                                                const int* __restrict__ mlist,
                                                const int* __restrict__ meta) {
  int e = blockIdx.x >> 6, j = blockIdx.x & 63;
  int cnt = meta[e];
  if (j * 128 >= cnt) return;
  int base = meta[8 + e];
  int tid = threadIdx.x, wave = tid >> 6, lane = tid & 63;
  int wm = wave >> 1, wn = wave & 1, quad = lane >> 4, l16 = lane & 15;
  int n0 = blockIdx.y * 128;
  const short* Bt = W1t + (size_t)e * DFF * DM;

  // per-lane fragment base pointers (advance by k elements)
  const short* ap[4]; const short* bp[4];
  #pragma unroll
  for (int mi = 0; mi < 4; mi++) {
    int rl = j * 128 + wm * 64 + mi * 16 + l16;
    int tok = mlist[base + (rl < cnt ? rl : cnt - 1)];
    ap[mi] = A + (size_t)tok * DM + quad * 8;
  }
  #pragma unroll
  for (int ni = 0; ni < 4; ni++)
    bp[ni] = Bt + (size_t)(n0 + wn * 64 + ni * 16 + l16) * DM + quad * 8;

  f32x4 acc[4][4];
  #pragma unroll
  for (int i = 0; i < 4; i++)
    #pragma unroll
    for (int jj = 0; jj < 4; jj++) acc[i][jj] = (f32x4){0.f, 0.f, 0.f, 0.f};

  bfrag a0[4], b0[4], a1[4], b1f[4];
  #pragma unroll
  for (int i = 0; i < 4; i++) { a0[i] = *(const bfrag*)(ap[i]); b0[i] = *(const bfrag*)(bp[i]); }

  for (int kt = 0; kt < DM; kt += 64) {
    #pragma unroll
    for (int i = 0; i < 4; i++) {
      a1[i]  = *(const bfrag*)(ap[i] + kt + 32);
      b1f[i] = *(const bfrag*)(bp[i] + kt + 32);
    }
    #pragma unroll
    for (int mi = 0; mi < 4; mi++)
      #pragma unroll
      for (int ni = 0; ni < 4; ni++)
        acc[mi][ni] = __builtin_amdgcn_mfma_f32_16x16x32_bf16(a0[mi], b0[ni], acc[mi][ni], 0, 0, 0);
    if (kt + 64 < DM) {
      #pragma unroll
      for (int i = 0; i < 4; i++) {
        a0[i] = *(const bfrag*)(ap[i] + kt + 64);
        b0[i] = *(const bfrag*)(bp[i] + kt + 64);
      }
    }
    #pragma unroll
    for (int mi = 0; mi < 4; mi++)
      #pragma unroll
      for (int ni = 0; ni < 4; ni++)
        acc[mi][ni] = __builtin_amdgcn_mfma_f32_16x16x32_bf16(a1[mi], b1f[ni], acc[mi][ni], 0, 0, 0);
  }
  const float* bb = b1 + (size_t)e * DFF;
  #pragma unroll
  for (int mi = 0; mi < 4; mi++) {
    int rbase = base + j * 128 + wm * 64 + mi * 16 + quad * 4;
    #pragma unroll
    for (int ni = 0; ni < 4; ni++) {
      int col = n0 + wn * 64 + ni * 16 + l16;
      float bv = bb[col];
      #pragma unroll
      for (int r = 0; r < 4; r++)
        H[(size_t)(rbase + r) * DFF + col] = f2bf(fast_gelu(acc[mi][ni][r] + bv));
    }
  }
}

// ---------------- GEMM2: partial[hrow] = bf16(wrow * (H[hrow] @ W2^T + b2)) ----------------
__global__ __launch_bounds__(256) void gemm2_sp(const short* __restrict__ H,
                                                const short* __restrict__ W2t,
                                                const float* __restrict__ b2,
                                                short* __restrict__ partial,
                                                const float* __restrict__ wrow,
                                                const int* __restrict__ meta) {
  int e = blockIdx.x >> 6, j = blockIdx.x & 63;
  int cnt = meta[e];
  if (j * 128 >= cnt) return;
  int base = meta[8 + e];
  int tid = threadIdx.x, wave = tid >> 6, lane = tid & 63;
  int wm = wave >> 1, wn = wave & 1, quad = lane >> 4, l16 = lane & 15;
  int n0 = blockIdx.y * 128;
  const short* Bt = W2t + (size_t)e * DM * DFF;

  const short* ap[4]; const short* bp[4];
  #pragma unroll
  for (int mi = 0; mi < 4; mi++)
    ap[mi] = H + (size_t)(base + j * 128 + wm * 64 + mi * 16 + l16) * DFF + quad * 8;
  #pragma unroll
  for (int ni = 0; ni < 4; ni++)
    bp[ni] = Bt + (size_t)(n0 + wn * 64 + ni * 16 + l16) * DFF + quad * 8;

  f32x4 acc[4][4];
  #pragma unroll
  for (int i = 0; i < 4; i++)
    #pragma unroll
    for (int jj = 0; jj < 4; jj++) acc[i][jj] = (f32x4){0.f, 0.f, 0.f, 0.f};

  bfrag a0[4], b0[4], a1[4], b1f[4];
  #pragma unroll
  for (int i = 0; i < 4; i++) { a0[i] = *(const bfrag*)(ap[i]); b0[i] = *(const bfrag*)(bp[i]); }

  for (int kt = 0; kt < DFF; kt += 64) {
    #pragma unroll
    for (int i = 0; i < 4; i++) {
      a1[i]  = *(const bfrag*)(ap[i] + kt + 32);
      b1f[i] = *(const bfrag*)(bp[i] + kt + 32);
    }
    #pragma unroll
    for (int mi = 0; mi < 4; mi++)
      #pragma unroll
      for (int ni = 0; ni < 4; ni++)
        acc[mi][ni] = __builtin_amdgcn_mfma_f32_16x16x32_bf16(a0[mi], b0[ni], acc[mi][ni], 0, 0, 0);
    if (kt + 64 < DFF) {
      #pragma unroll
      for (int i = 0; i < 4; i++) {
        a0[i] = *(const bfrag*)(ap[i] + kt + 64);
        b0[i] = *(const bfrag*)(bp[i] + kt + 64);
      }
    }
    #pragma unroll
    for (int mi = 0; mi < 4; mi++)
      #pragma unroll
      for (int ni = 0; ni < 4; ni++)
        acc[mi][ni] = __builtin_amdgcn_mfma_f32_16x16x32_bf16(a1[mi], b1f[ni], acc[mi][ni], 0, 0, 0);
  }
  const float* bb = b2 + (size_t)e * DM;
  #pragma unroll
  for (int mi = 0; mi < 4; mi++) {
    int rbase = base + j * 128 + wm * 64 + mi * 16 + quad * 4;
    #pragma unroll
    for (int ni = 0; ni < 4; ni++) {
      int col = n0 + wn * 64 + ni * 16 + l16;
      float bv = bb[col];
      #pragma unroll
      for (int r = 0; r < 4; r++) {
        float w = wrow[rbase + r];
        partial[(size_t)(rbase + r) * DM + col] = f2bf(w * (acc[mi][ni][r] + bv));
      }
    }
  }
}

// ---------------- combine: out[t] = sum of token's weighted partials ----------------
__global__ __launch_bounds__(256) void combine_kernel(const short* __restrict__ partial,
                                                      const int* __restrict__ arow,
                                                      float* __restrict__ out) {
  int gid = blockIdx.x * 256 + threadIdx.x;
  int t = gid >> 6, c0 = (gid & 63) << 3;
  const int* ar = arow + t * 4;
  float o[8];
  #pragma unroll
  for (int k = 0; k < 8; k++) o[k] = 0.f;
  #pragma unroll
  for (int s = 0; s < 4; s++) {
    int a = ar[s];
    if (a >= 0) {
      union { u32x4 v; short s16[8]; } buf;
      buf.v = *(const u32x4*)(partial + (size_t)a * DM + c0);
      #pragma unroll
      for (int k = 0; k < 8; k++) o[k] += bf2f(buf.s16[k]);
    }
  }
  float* op = out + (size_t)t * DM + c0;
  *(f32x4*)op = (f32x4){o[0], o[1], o[2], o[3]};
  *(f32x4*)(op + 4) = (f32x4){o[4], o[5], o[6], o[7]};
}

extern "C" void kernel_launch(void* const* d_in, const int* in_sizes, int n_in,
                              void* d_out, int out_size, void* d_ws, size_t ws_size,
                              hipStream_t stream) {
  const float* x  = (const float*)d_in[0];
  const float* rw = (const float*)d_in[1];
  const float* W1 = (const float*)d_in[2];
  const float* b1 = (const float*)d_in[3];
  const float* W2 = (const float*)d_in[4];
  const float* b2 = (const float*)d_in[5];
  float* out = (float*)d_out;

  char* base_p = (char*)d_ws; char* p = base_p;
  auto carve = [&](size_t bytes) { char* r = p; p += (bytes + 255) & ~(size_t)255; return r; };
  short* xb    = (short*)carve((size_t)NTOK * DM * 2);
  short* w1b   = (short*)carve((size_t)NE * DM * DFF * 2);  // [e][DFF][DM]
  short* w2b   = (short*)carve((size_t)NE * DFF * DM * 2);  // [e][DM][DFF]
  int*   sel_e = (int*)carve((size_t)NTOK * 4 * 4);
  float* sel_w = (float*)carve((size_t)NTOK * 4 * 4);
  float* part  = (float*)carve(256 * 16 * 4);
  int*   meta  = (int*)carve(64 * 4);
  int*   arow  = (int*)carve((size_t)NTOK * 4 * 4);
  int*   mlist = (int*)carve((size_t)ROWCAP * 4);
  float* wrow  = (float*)carve((size_t)ROWCAP * 4);
  short* Hbig  = (short*)carve((size_t)ROWCAP * DFF * 2);
  short* partial = (short*)carve((size_t)ROWCAP * DM * 2);

  cvt_kernel<<<(NTOK * DM / 4 + 255) / 256, 256, 0, stream>>>(x, xb, NTOK * DM / 4);
  cvtT_kernel<<<dim3(DM / 32, DFF / 32, NE), 256, 0, stream>>>(W1, w1b, DM, DFF);
  cvtT_kernel<<<dim3(DFF / 32, DM / 32, NE), 256, 0, stream>>>(W2, w2b, DFF, DM);
  router_kernel<<<256, 256, 0, stream>>>(x, rw, sel_e, sel_w, part);
  prep_kernel<<<1, 256, 0, stream>>>(part, out + (size_t)NTOK * DM, meta);
  build_kernel<<<256, 256, 0, stream>>>(sel_e, sel_w, meta, mlist, wrow, arow);
  gemm1_sp<<<dim3(NE * 64, DFF / 128), 256, 0, stream>>>(xb, w1b, b1, Hbig, mlist, meta);
  gemm2_sp<<<dim3(NE * 64, DM / 128), 256, 0, stream>>>(Hbig, w2b, b2, partial, wrow, meta);
  combine_kernel<<<NTOK * DM / 8 / 256, 256, 0, stream>>>(partial, arow, out);
}

// Round 8
// 539.374 us; speedup vs baseline: 1.6362x; 1.6362x over previous
//
#include <hip/hip_runtime.h>
#include <hip/hip_bf16.h>
#include <math.h>

#define NTOK 8192
#define DM 512
#define DFF 2048
#define NE 8
#define ROWCAP 34816   // 32768 assignments max + 8*256 granule padding

typedef __attribute__((ext_vector_type(8))) short bfrag;
typedef __attribute__((ext_vector_type(4))) float f32x4;
typedef __attribute__((ext_vector_type(4))) unsigned int u32x4;
typedef __attribute__((ext_vector_type(4))) short s16x4;

// async global->LDS, 16B/lane; LDS dest = wave-uniform base + lane*16 (global addr may be per-lane)
#define GLD_LDS16(gp, lp) __builtin_amdgcn_global_load_lds( \
    (const __attribute__((address_space(1))) void*)(gp),    \
    (__attribute__((address_space(3))) void*)(lp), 16, 0, 0)

__device__ __forceinline__ short f2bf(float f) {
  unsigned u = __builtin_bit_cast(unsigned, f);
  u += 0x7fffu + ((u >> 16) & 1u);
  return (short)(u >> 16);
}
__device__ __forceinline__ float bf2f(short s) {
  unsigned u = ((unsigned)(unsigned short)s) << 16;
  return __builtin_bit_cast(float, u);
}
// tanh-form GELU via hw exp2+rcp (~7 ops). max |diff vs erf-gelu| ~5e-4.
__device__ __forceinline__ float fast_gelu(float v) {
  float u = fmaf(v * v * v, 0.044715f, v) * 0.7978845608f;
  float ex = __builtin_amdgcn_exp2f(u * -2.8853900818f);
  return v * __builtin_amdgcn_rcpf(1.f + ex);
}

// ---------------- fp32 -> bf16 conversion ----------------
__global__ __launch_bounds__(256) void cvt_kernel(const float* __restrict__ in,
                                                  short* __restrict__ o, int n4) {
  int i = blockIdx.x * 256 + threadIdx.x;
  if (i >= n4) return;
  f32x4 v = ((const f32x4*)in)[i];
  s16x4 s;
  #pragma unroll
  for (int j = 0; j < 4; j++) s[j] = f2bf(v[j]);
  ((s16x4*)o)[i] = s;
}

// ---------------- fp32 -> bf16 transpose-convert ----------------
__global__ __launch_bounds__(256) void cvtT_kernel(const float* __restrict__ in,
                                                   short* __restrict__ o, int R, int C) {
  __shared__ float t[32][33];
  size_t eoff = (size_t)blockIdx.z * R * C;
  in += eoff; o += eoff;
  int r0 = blockIdx.x * 32, c0 = blockIdx.y * 32;
  int tx = threadIdx.x & 31, ty = threadIdx.x >> 5;
  #pragma unroll
  for (int i = 0; i < 32; i += 8)
    t[ty + i][tx] = in[(size_t)(r0 + ty + i) * C + c0 + tx];
  __syncthreads();
  #pragma unroll
  for (int i = 0; i < 32; i += 8)
    o[(size_t)(c0 + ty + i) * R + r0 + tx] = f2bf(t[tx][ty + i]);
}

// ---------------- router ----------------
__global__ __launch_bounds__(256) void router_kernel(const float* __restrict__ x,
                                                     const float* __restrict__ rw,
                                                     int* __restrict__ sel_e,
                                                     float* __restrict__ sel_w,
                                                     float* __restrict__ part) {
  __shared__ float s_cnt[NE], s_ps[NE];
  int tid = threadIdx.x;
  if (tid < NE) { s_cnt[tid] = 0.f; s_ps[tid] = 0.f; }
  __syncthreads();
  int wave = tid >> 6, lane = tid & 63;
  float myc[NE], myp[NE];
  #pragma unroll
  for (int e = 0; e < NE; e++) { myc[e] = 0.f; myp[e] = 0.f; }

  for (int i = 0; i < 8; i++) {
    int token = blockIdx.x * 32 + wave * 8 + i;
    const float* xt = x + (size_t)token * DM;
    float acc[NE];
    #pragma unroll
    for (int e = 0; e < NE; e++) acc[e] = 0.f;
    #pragma unroll
    for (int kk = 0; kk < DM / 64; kk++) {
      int k = kk * 64 + lane;
      float xv = xt[k];
      f32x4 r0 = *(const f32x4*)(rw + k * NE);
      f32x4 r1 = *(const f32x4*)(rw + k * NE + 4);
      acc[0] += xv * r0[0]; acc[1] += xv * r0[1]; acc[2] += xv * r0[2]; acc[3] += xv * r0[3];
      acc[4] += xv * r1[0]; acc[5] += xv * r1[1]; acc[6] += xv * r1[2]; acc[7] += xv * r1[3];
    }
    #pragma unroll
    for (int off = 32; off >= 1; off >>= 1) {
      #pragma unroll
      for (int e = 0; e < NE; e++) acc[e] += __shfl_xor(acc[e], off, 64);
    }
    float mx = acc[0];
    #pragma unroll
    for (int e = 1; e < NE; e++) mx = fmaxf(mx, acc[e]);
    float p[NE]; float sum = 0.f;
    #pragma unroll
    for (int e = 0; e < NE; e++) { p[e] = expf(acc[e] - mx); sum += p[e]; }
    float inv = 1.f / sum;
    #pragma unroll
    for (int e = 0; e < NE; e++) p[e] *= inv;
    float sp[4]; int si[4]; unsigned used = 0;
    #pragma unroll
    for (int s = 0; s < 4; s++) {
      float bp = -1.f; int bi = 0;
      #pragma unroll
      for (int e = 0; e < NE; e++)
        if (!((used >> e) & 1u) && p[e] > bp) { bp = p[e]; bi = e; }
      used |= 1u << bi; sp[s] = bp; si[s] = bi;
    }
    float csum = 0.f, wsum = 0.f; bool keep[4];
    #pragma unroll
    for (int s = 0; s < 4; s++) {
      keep[s] = (s < 1) || (csum < 0.9f);
      csum += sp[s];
      if (keep[s]) wsum += sp[s];
    }
    wsum = fmaxf(wsum, 1e-9f);
    if (lane == 0) {
      #pragma unroll
      for (int s = 0; s < 4; s++) {
        sel_e[token * 4 + s] = keep[s] ? si[s] : -1;
        sel_w[token * 4 + s] = keep[s] ? sp[s] / wsum : 0.f;
      }
      #pragma unroll
      for (int e = 0; e < NE; e++) myp[e] += p[e];
      #pragma unroll
      for (int s = 0; s < 4; s++) if (keep[s]) myc[si[s]] += 1.f;
    }
  }
  if (lane == 0) {
    #pragma unroll
    for (int e = 0; e < NE; e++) { atomicAdd(&s_cnt[e], myc[e]); atomicAdd(&s_ps[e], myp[e]); }
  }
  __syncthreads();
  if (tid < NE) {
    part[blockIdx.x * 16 + tid] = s_cnt[tid];
    part[blockIdx.x * 16 + 8 + tid] = s_ps[tid];
  }
}

// ---------------- prep: parallel stat reduction -> aux + expert bases (256-aligned) ----------------
__global__ __launch_bounds__(256) void prep_kernel(const float* __restrict__ part,
                                                   float* __restrict__ auxp,
                                                   int* __restrict__ meta) {
  __shared__ float red[16];
  int tid = threadIdx.x;
  if (tid < 16) red[tid] = 0.f;
  __syncthreads();
  float s = 0.f;
  #pragma unroll
  for (int m = 0; m < 16; m++) s += part[tid + m * 256];
  atomicAdd(&red[tid & 15], s);
  __syncthreads();
  if (tid == 0) {
    float tot = 0.f;
    for (int e = 0; e < NE; e++) tot += red[e];
    float t = fmaxf(tot, 1.f), acc = 0.f;
    for (int e = 0; e < NE; e++) acc += (red[e] / t) * (red[NE + e] / (float)NTOK);
    auxp[0] = 0.01f * (float)NE * acc;
    int off = 0;
    for (int e = 0; e < NE; e++) {
      int c = (int)(red[e] + 0.5f);
      meta[e] = c; meta[8 + e] = off;
      off += (c + 255) & ~255;   // 256-granule padding (M-tile = 256)
    }
  }
  if (tid < NE) meta[16 + tid] = 0;
}

// ---------------- build compact assignment lists ----------------
__global__ __launch_bounds__(256) void build_kernel(const int* __restrict__ sel_e,
                                                    const float* __restrict__ sel_w,
                                                    int* __restrict__ meta,
                                                    int* __restrict__ mlist,
                                                    float* __restrict__ wrow,
                                                    int* __restrict__ arow) {
  __shared__ int lcnt[NE], roff[NE];
  int tid = threadIdx.x;
  if (tid < NE) lcnt[tid] = 0;
  __syncthreads();
  int t = blockIdx.x * 32 + tid;
  int slots[4], es[4];
  bool active = tid < 32;
  if (active) {
    #pragma unroll
    for (int s = 0; s < 4; s++) {
      es[s] = sel_e[t * 4 + s];
      slots[s] = (es[s] >= 0) ? atomicAdd(&lcnt[es[s]], 1) : -1;
    }
  }
  __syncthreads();
  if (tid < NE) roff[tid] = atomicAdd(&meta[16 + tid], lcnt[tid]);
  __syncthreads();
  if (active) {
    #pragma unroll
    for (int s = 0; s < 4; s++) {
      int e = es[s];
      if (e >= 0) {
        int hrow = meta[8 + e] + roff[e] + slots[s];
        mlist[hrow] = t;
        wrow[hrow] = sel_w[t * 4 + s];
        arow[t * 4 + s] = hrow;
      } else {
        arow[t * 4 + s] = -1;
      }
    }
  }
}

// ============ 256x128 dbuf GEMMs, XCD-pinned per expert ============
// 1D grid, expert = blockIdx.x & 7 -> under the %8 round-robin dispatch
// heuristic each XCD serves one expert; its W-slice (2.1 MB bf16) stays
// L2-resident. Within an XCD, n0 varies fastest (A-tile L2 reuse across n0).
// Block tile 256x128 (FM=8 x FN=4 per wave, waves 2x2), BK=32, LDS dbuf
// (As 2x16KB + Bs 2x8KB = 48 KB), one barrier per K-iter, prefetch after it.

// ---------------- GEMM1: H[hrow] = bf16(gelu(x[tok] @ W1^T + b1)) ----------------
__global__ __launch_bounds__(256) void gemm1_sp(const short* __restrict__ A,
                                                const short* __restrict__ W1t,
                                                const float* __restrict__ b1,
                                                short* __restrict__ H,
                                                const int* __restrict__ mlist,
                                                const int* __restrict__ meta) {
  __shared__ __align__(16) short As[2 * 256 * 32];
  __shared__ __align__(16) short Bs[2 * 128 * 32];
  int bid = blockIdx.x;
  int e = bid & 7, t = bid >> 3;
  int n0 = (t & 15) * 128, j = t >> 4;       // n0 fastest within XCD
  int cnt = meta[e];
  if (j * 256 >= cnt) return;
  int base = meta[8 + e];
  int tid = threadIdx.x, wave = tid >> 6, lane = tid & 63;
  int wm = wave >> 1, wn = wave & 1, quad = lane >> 4, l16 = lane & 15;
  const short* Bt = W1t + (size_t)e * DFF * DM;

  // staging: chunk c = (g*4+wave)*64 + lane -> row c>>2, 16B seg c&3
  const short* ag[4]; const short* bg[2];
  #pragma unroll
  for (int g = 0; g < 4; g++) {
    int c = (g * 4 + wave) * 64 + lane;
    int row = c >> 2, seg = c & 3;
    int rl = j * 256 + row;
    int tok = mlist[base + (rl < cnt ? rl : cnt - 1)];
    ag[g] = A + (size_t)tok * DM + seg * 8;
  }
  #pragma unroll
  for (int g = 0; g < 2; g++) {
    int c = (g * 4 + wave) * 64 + lane;
    int row = c >> 2, seg = c & 3;
    bg[g] = Bt + (size_t)(n0 + row) * DM + seg * 8;
  }

  f32x4 acc[8][4];
  #pragma unroll
  for (int i = 0; i < 8; i++)
    #pragma unroll
    for (int jj = 0; jj < 4; jj++) acc[i][jj] = (f32x4){0.f, 0.f, 0.f, 0.f};

  // prologue: stage tile 0 into buf 0
  #pragma unroll
  for (int g = 0; g < 4; g++) GLD_LDS16(ag[g], As + (g * 4 + wave) * 512);
  #pragma unroll
  for (int g = 0; g < 2; g++) GLD_LDS16(bg[g], Bs + (g * 4 + wave) * 512);

  for (int kt = 0; kt < DM; kt += 32) {
    int cur = (kt >> 5) & 1;
    __syncthreads();               // buf cur ready; prev compute done
    if (kt + 32 < DM) {
      int na = (cur ^ 1) * 8192, nb = (cur ^ 1) * 4096;
      #pragma unroll
      for (int g = 0; g < 4; g++) GLD_LDS16(ag[g] + kt + 32, As + na + (g * 4 + wave) * 512);
      #pragma unroll
      for (int g = 0; g < 2; g++) GLD_LDS16(bg[g] + kt + 32, Bs + nb + (g * 4 + wave) * 512);
    }
    const short* Ab = As + cur * 8192;
    const short* Bb = Bs + cur * 4096;
    bfrag afr[8], bfr[4];
    #pragma unroll
    for (int mi = 0; mi < 8; mi++)
      afr[mi] = *(const bfrag*)(Ab + (wm * 128 + mi * 16 + l16) * 32 + quad * 8);
    #pragma unroll
    for (int ni = 0; ni < 4; ni++)
      bfr[ni] = *(const bfrag*)(Bb + (wn * 64 + ni * 16 + l16) * 32 + quad * 8);
    #pragma unroll
    for (int mi = 0; mi < 8; mi++)
      #pragma unroll
      for (int ni = 0; ni < 4; ni++)
        acc[mi][ni] = __builtin_amdgcn_mfma_f32_16x16x32_bf16(afr[mi], bfr[ni], acc[mi][ni], 0, 0, 0);
  }
  const float* bb = b1 + (size_t)e * DFF;
  #pragma unroll
  for (int mi = 0; mi < 8; mi++) {
    int rbase = base + j * 256 + wm * 128 + mi * 16 + quad * 4;
    #pragma unroll
    for (int ni = 0; ni < 4; ni++) {
      int col = n0 + wn * 64 + ni * 16 + l16;
      float bv = bb[col];
      #pragma unroll
      for (int r = 0; r < 4; r++)
        H[(size_t)(rbase + r) * DFF + col] = f2bf(fast_gelu(acc[mi][ni][r] + bv));
    }
  }
}

// ---------------- GEMM2: partial[hrow] = bf16(wrow * (H[hrow] @ W2^T + b2)) ----------------
__global__ __launch_bounds__(256) void gemm2_sp(const short* __restrict__ H,
                                                const short* __restrict__ W2t,
                                                const float* __restrict__ b2,
                                                short* __restrict__ partial,
                                                const float* __restrict__ wrow,
                                                const int* __restrict__ meta) {
  __shared__ __align__(16) short As[2 * 256 * 32];
  __shared__ __align__(16) short Bs[2 * 128 * 32];
  int bid = blockIdx.x;
  int e = bid & 7, t = bid >> 3;
  int n0 = (t & 3) * 128, j = t >> 2;
  int cnt = meta[e];
  if (j * 256 >= cnt) return;
  int base = meta[8 + e];
  int tid = threadIdx.x, wave = tid >> 6, lane = tid & 63;
  int wm = wave >> 1, wn = wave & 1, quad = lane >> 4, l16 = lane & 15;
  const short* Bt = W2t + (size_t)e * DM * DFF;

  const short* ag[4]; const short* bg[2];
  #pragma unroll
  for (int g = 0; g < 4; g++) {
    int c = (g * 4 + wave) * 64 + lane;
    int row = c >> 2, seg = c & 3;
    ag[g] = H + (size_t)(base + j * 256 + row) * DFF + seg * 8;
  }
  #pragma unroll
  for (int g = 0; g < 2; g++) {
    int c = (g * 4 + wave) * 64 + lane;
    int row = c >> 2, seg = c & 3;
    bg[g] = Bt + (size_t)(n0 + row) * DFF + seg * 8;
  }

  f32x4 acc[8][4];
  #pragma unroll
  for (int i = 0; i < 8; i++)
    #pragma unroll
    for (int jj = 0; jj < 4; jj++) acc[i][jj] = (f32x4){0.f, 0.f, 0.f, 0.f};

  #pragma unroll
  for (int g = 0; g < 4; g++) GLD_LDS16(ag[g], As + (g * 4 + wave) * 512);
  #pragma unroll
  for (int g = 0; g < 2; g++) GLD_LDS16(bg[g], Bs + (g * 4 + wave) * 512);

  for (int kt = 0; kt < DFF; kt += 32) {
    int cur = (kt >> 5) & 1;
    __syncthreads();
    if (kt + 32 < DFF) {
      int na = (cur ^ 1) * 8192, nb = (cur ^ 1) * 4096;
      #pragma unroll
      for (int g = 0; g < 4; g++) GLD_LDS16(ag[g] + kt + 32, As + na + (g * 4 + wave) * 512);
      #pragma unroll
      for (int g = 0; g < 2; g++) GLD_LDS16(bg[g] + kt + 32, Bs + nb + (g * 4 + wave) * 512);
    }
    const short* Ab = As + cur * 8192;
    const short* Bb = Bs + cur * 4096;
    bfrag afr[8], bfr[4];
    #pragma unroll
    for (int mi = 0; mi < 8; mi++)
      afr[mi] = *(const bfrag*)(Ab + (wm * 128 + mi * 16 + l16) * 32 + quad * 8);
    #pragma unroll
    for (int ni = 0; ni < 4; ni++)
      bfr[ni] = *(const bfrag*)(Bb + (wn * 64 + ni * 16 + l16) * 32 + quad * 8);
    #pragma unroll
    for (int mi = 0; mi < 8; mi++)
      #pragma unroll
      for (int ni = 0; ni < 4; ni++)
        acc[mi][ni] = __builtin_amdgcn_mfma_f32_16x16x32_bf16(afr[mi], bfr[ni], acc[mi][ni], 0, 0, 0);
  }
  const float* bb = b2 + (size_t)e * DM;
  #pragma unroll
  for (int mi = 0; mi < 8; mi++) {
    int rbase = base + j * 256 + wm * 128 + mi * 16 + quad * 4;
    #pragma unroll
    for (int ni = 0; ni < 4; ni++) {
      int col = n0 + wn * 64 + ni * 16 + l16;
      float bv = bb[col];
      #pragma unroll
      for (int r = 0; r < 4; r++) {
        float w = wrow[rbase + r];
        partial[(size_t)(rbase + r) * DM + col] = f2bf(w * (acc[mi][ni][r] + bv));
      }
    }
  }
}

// ---------------- combine: out[t] = sum of token's weighted partials ----------------
__global__ __launch_bounds__(256) void combine_kernel(const short* __restrict__ partial,
                                                      const int* __restrict__ arow,
                                                      float* __restrict__ out) {
  int gid = blockIdx.x * 256 + threadIdx.x;
  int t = gid >> 6, c0 = (gid & 63) << 3;
  const int* ar = arow + t * 4;
  float o[8];
  #pragma unroll
  for (int k = 0; k < 8; k++) o[k] = 0.f;
  #pragma unroll
  for (int s = 0; s < 4; s++) {
    int a = ar[s];
    if (a >= 0) {
      union { u32x4 v; short s16[8]; } buf;
      buf.v = *(const u32x4*)(partial + (size_t)a * DM + c0);
      #pragma unroll
      for (int k = 0; k < 8; k++) o[k] += bf2f(buf.s16[k]);
    }
  }
  float* op = out + (size_t)t * DM + c0;
  *(f32x4*)op = (f32x4){o[0], o[1], o[2], o[3]};
  *(f32x4*)(op + 4) = (f32x4){o[4], o[5], o[6], o[7]};
}

extern "C" void kernel_launch(void* const* d_in, const int* in_sizes, int n_in,
                              void* d_out, int out_size, void* d_ws, size_t ws_size,
                              hipStream_t stream) {
  const float* x  = (const float*)d_in[0];
  const float* rw = (const float*)d_in[1];
  const float* W1 = (const float*)d_in[2];
  const float* b1 = (const float*)d_in[3];
  const float* W2 = (const float*)d_in[4];
  const float* b2 = (const float*)d_in[5];
  float* out = (float*)d_out;

  char* base_p = (char*)d_ws; char* p = base_p;
  auto carve = [&](size_t bytes) { char* r = p; p += (bytes + 255) & ~(size_t)255; return r; };
  short* xb    = (short*)carve((size_t)NTOK * DM * 2);
  short* w1b   = (short*)carve((size_t)NE * DM * DFF * 2);  // [e][DFF][DM]
  short* w2b   = (short*)carve((size_t)NE * DFF * DM * 2);  // [e][DM][DFF]
  int*   sel_e = (int*)carve((size_t)NTOK * 4 * 4);
  float* sel_w = (float*)carve((size_t)NTOK * 4 * 4);
  float* part  = (float*)carve(256 * 16 * 4);
  int*   meta  = (int*)carve(64 * 4);
  int*   arow  = (int*)carve((size_t)NTOK * 4 * 4);
  int*   mlist = (int*)carve((size_t)ROWCAP * 4);
  float* wrow  = (float*)carve((size_t)ROWCAP * 4);
  short* Hbig  = (short*)carve((size_t)ROWCAP * DFF * 2);
  short* partial = (short*)carve((size_t)ROWCAP * DM * 2);

  cvt_kernel<<<(NTOK * DM / 4 + 255) / 256, 256, 0, stream>>>(x, xb, NTOK * DM / 4);
  cvtT_kernel<<<dim3(DM / 32, DFF / 32, NE), 256, 0, stream>>>(W1, w1b, DM, DFF);
  cvtT_kernel<<<dim3(DFF / 32, DM / 32, NE), 256, 0, stream>>>(W2, w2b, DFF, DM);
  router_kernel<<<256, 256, 0, stream>>>(x, rw, sel_e, sel_w, part);
  prep_kernel<<<1, 256, 0, stream>>>(part, out + (size_t)NTOK * DM, meta);
  build_kernel<<<256, 256, 0, stream>>>(sel_e, sel_w, meta, mlist, wrow, arow);
  // grids: 1D, expert = bid&7 (XCD pin), n0 fastest, j (M-granule 256) slowest.
  // Jmax=32 covers worst case cnt_e = 8192; inactive (j*256>=cnt) blocks exit fast.
  gemm1_sp<<<8 * 16 * 32, 256, 0, stream>>>(xb, w1b, b1, Hbig, mlist, meta);
  gemm2_sp<<<8 * 4 * 32, 256, 0, stream>>>(Hbig, w2b, b2, partial, wrow, meta);
  combine_kernel<<<NTOK * DM / 8 / 256, 256, 0, stream>>>(partial, arow, out);
}